// Round 18
// baseline (336.559 us; speedup 1.0000x reference)
//
#include <hip/hip_runtime.h>
#include <hip/hip_bf16.h>

#define Bn 32
#define Ln 1024
#define En 512
#define On 512

typedef __attribute__((ext_vector_type(8))) short bf16x8;
typedef __attribute__((ext_vector_type(8))) _Float16 f16x8;
typedef __attribute__((ext_vector_type(4))) float f32x4;

__device__ __forceinline__ ushort f2bf(float x) {
    __hip_bfloat16 h = __float2bfloat16(x);
    return *reinterpret_cast<ushort*>(&h);
}
__device__ __forceinline__ ushort f2h(float x) {
    _Float16 h = (_Float16)x;
    return *reinterpret_cast<ushort*>(&h);
}

// MFMA dispatch: bits held in bf16x8; FP16 variant reinterprets as f16x8.
template <bool FP16>
__device__ __forceinline__ f32x4 frag_mfma(bf16x8 a, bf16x8 b, f32x4 c) {
    if constexpr (FP16)
        return __builtin_amdgcn_mfma_f32_16x16x32_f16(*(f16x8*)&a, *(f16x8*)&b, c, 0, 0, 0);
    else
        return __builtin_amdgcn_mfma_f32_16x16x32_bf16(a, b, c, 0, 0, 0);
}

// ---------------------------------------------------------------------------
// Stage a 128x32 16-bit tile into linear LDS [128][32] via global_load_lds.
// 256 threads * 2 issues * 16B = 8KB.
// ---------------------------------------------------------------------------
__device__ __forceinline__ void stage(ushort* dst, const ushort* src, size_t rstride) {
    const int tid = threadIdx.x;
#pragma unroll
    for (int cc = 0; cc < 2; ++cc) {
        const int c = tid + cc * 256;
        const ushort* g = src + (size_t)(c >> 2) * rstride + (c & 3) * 8;
        ushort* l = dst + ((size_t)(tid >> 6) * 64 + cc * 256) * 8;
        __builtin_amdgcn_global_load_lds(
            (const __attribute__((address_space(1))) unsigned int*)g,
            (__attribute__((address_space(3))) unsigned int*)l, 16, 0, 0);
    }
}

// ---------------------------------------------------------------------------
// Pipelined NT GEMM core (r6-proven schedule, plain 2-tile form): 128x128
// tile, BK=32, 256 threads, double-buffered LDS (32KB) + counted vmcnt +
// raw barriers. FP16 selects fp16 MFMA, else bf16.
// ---------------------------------------------------------------------------
template <bool FP16>
__device__ __forceinline__ void nt_core_pipe(const ushort* __restrict__ Ah,
                                             const ushort* __restrict__ Bh,
                                             size_t astr, size_t bstr, int Kd,
                                             f32x4 (&acc)[4][4]) {
    __shared__ ushort lds[2][2 * 4096];

    const int tid = threadIdx.x;
    const int lane = tid & 63, wave = tid >> 6;
    const int wr = (wave >> 1) * 64, wc = (wave & 1) * 64;
    const int ln = lane & 15, kb = (lane >> 4) * 8;
    const int NT = Kd >> 5;

    auto stage_all = [&](int kt, int slot) {
        const int k0 = kt * 32;
        stage(&lds[slot][0], Ah + k0, astr);
        stage(&lds[slot][4096], Bh + k0, bstr);
    };

    stage_all(0, 0);
    stage_all(1, 1);
    asm volatile("s_waitcnt vmcnt(4)" ::: "memory");
    __builtin_amdgcn_sched_barrier(0);
    __builtin_amdgcn_s_barrier();

    for (int t = 0; t < NT; ++t) {
        __builtin_amdgcn_sched_barrier(0);
        const int cur = t & 1;
        const ushort* sAh = &lds[cur][0];
        const ushort* sBh = &lds[cur][4096];

        bf16x8 bh[4];
#pragma unroll
        for (int n = 0; n < 4; ++n)
            bh[n] = *(const bf16x8*)&sBh[(size_t)(wc + n * 16 + ln) * 32 + kb];
#pragma unroll
        for (int m = 0; m < 4; ++m) {
            bf16x8 ah = *(const bf16x8*)&sAh[(size_t)(wr + m * 16 + ln) * 32 + kb];
#pragma unroll
            for (int n = 0; n < 4; ++n) acc[m][n] = frag_mfma<FP16>(ah, bh[n], acc[m][n]);
        }

        asm volatile("s_waitcnt lgkmcnt(0)" ::: "memory");
        __builtin_amdgcn_sched_barrier(0);
        __builtin_amdgcn_s_barrier();

        if (t + 2 < NT) {
            stage_all(t + 2, cur);
            asm volatile("s_waitcnt vmcnt(4)" ::: "memory");
            __builtin_amdgcn_sched_barrier(0);
            __builtin_amdgcn_s_barrier();
        } else if (t + 1 < NT) {
            asm volatile("s_waitcnt vmcnt(0)" ::: "memory");
            __builtin_amdgcn_sched_barrier(0);
            __builtin_amdgcn_s_barrier();
        }
    }
    asm volatile("s_waitcnt vmcnt(0)" ::: "memory");  // drain (short-NT safety)
}

// ---------------------------------------------------------------------------
// Merged prep kernel (grid 8512, 256 thr):
//   blocks [0, 8192)      : X fp32 -> Xf fp16
//   blocks [8192, 8448)   : Wv -> wv [o][e] fp16 transposed (16x16 tiles)
//   blocks [8448, 8512)   : Mt = (Wq*Wk^T)^T fp16 (8x8 grid of 64x64 tiles)
// All three are independent (read-only inputs, disjoint outputs).
// ---------------------------------------------------------------------------
__global__ __launch_bounds__(256) void prep_kernel(const float* __restrict__ X,
                                                   const float* __restrict__ Wq,
                                                   const float* __restrict__ Wk,
                                                   const float* __restrict__ Wv,
                                                   ushort* __restrict__ Xf,
                                                   ushort* __restrict__ wv,
                                                   ushort* __restrict__ Mt) {
    const int blk = blockIdx.x;
    const int tid = threadIdx.x;

    if (blk < 8192) {  // ---- convert_x ----
        const int g = blk * 256 + tid;
        const int row = g >> 6;
        const int k0 = (g & 63) * 8;
        const float* xp = X + (size_t)row * En + k0;
        float4 x0 = *(const float4*)xp;
        float4 x1 = *(const float4*)(xp + 4);
        float xs[8] = {x0.x, x0.y, x0.z, x0.w, x1.x, x1.y, x1.z, x1.w};
        bf16x8 h;
#pragma unroll
        for (int j = 0; j < 8; ++j) h[j] = (short)f2h(xs[j]);
        *(bf16x8*)(Xf + (size_t)row * En + k0) = h;
        return;
    }

    if (blk < 8448) {  // ---- convert_wv ----
        __shared__ float tile[32][33];
        const int idx = blk - 8192;           // [0,256)
        const int n0 = (idx & 15) * 32, k0 = (idx >> 4) * 32;
        const int r = tid >> 3, c4 = (tid & 7) * 4;
        float4 w = *(const float4*)&Wv[(size_t)(k0 + r) * On + n0 + c4];
        tile[r][c4 + 0] = w.x;
        tile[r][c4 + 1] = w.y;
        tile[r][c4 + 2] = w.z;
        tile[r][c4 + 3] = w.w;
        __syncthreads();
        ushort4 hs;
        ushort* hp = &hs.x;
#pragma unroll
        for (int jj = 0; jj < 4; ++jj) hp[jj] = f2h(tile[c4 + jj][r]);
        *(ushort4*)&wv[(size_t)(n0 + r) * En + k0 + c4] = hs;
        return;
    }

    // ---- compute_m: Mt[e2][e1] = sum_o Wk[e2][o]*Wq[e1][o] ----
    {
        __shared__ float As[16][65], Bs[16][65];
        const int idx = blk - 8448;  // [0,64)
        const int row0 = (idx >> 3) * 64;
        const int col0 = (idx & 7) * 64;
        const int tx = tid & 15, ty = tid >> 4;
        const int ar = tid >> 2, ac = (tid & 3) * 4;

        float acc[4][4] = {};
        for (int k0 = 0; k0 < On; k0 += 16) {
            float4 av = *(const float4*)&Wk[(size_t)(row0 + ar) * On + k0 + ac];
            As[ac + 0][ar] = av.x;
            As[ac + 1][ar] = av.y;
            As[ac + 2][ar] = av.z;
            As[ac + 3][ar] = av.w;
            float4 bv = *(const float4*)&Wq[(size_t)(col0 + ar) * On + k0 + ac];
            Bs[ac + 0][ar] = bv.x;
            Bs[ac + 1][ar] = bv.y;
            Bs[ac + 2][ar] = bv.z;
            Bs[ac + 3][ar] = bv.w;
            __syncthreads();
#pragma unroll
            for (int kk = 0; kk < 16; ++kk) {
                float a[4], b[4];
#pragma unroll
                for (int x = 0; x < 4; ++x) {
                    a[x] = As[kk][ty * 4 + x];
                    b[x] = Bs[kk][tx * 4 + x];
                }
#pragma unroll
                for (int ii = 0; ii < 4; ++ii)
#pragma unroll
                    for (int jj = 0; jj < 4; ++jj) acc[ii][jj] = fmaf(a[ii], b[jj], acc[ii][jj]);
            }
            __syncthreads();
        }

#pragma unroll
        for (int ii = 0; ii < 4; ++ii)
#pragma unroll
            for (int jj = 0; jj < 4; ++jj) {
                const int i = row0 + ty * 4 + ii;
                const int j = col0 + tx * 4 + jj;
                Mt[(size_t)i * En + j] = f2h(acc[ii][jj]);
            }
    }
}

// ---------------------------------------------------------------------------
// Pass 1 (merged): n<1024: Y = X*M (fp16) -> Yf; n>=1024: V = X*Wv^T (fp16)
// -> vt[b][o][l] bf16. Both paths plain fp16 nt_core_pipe, 32KB LDS.
// Batch-aligned XCD swizzle; skips fully-masked row panels.
// ---------------------------------------------------------------------------
__global__ __launch_bounds__(256) void gemm_yv(const ushort* __restrict__ Xf,
                                               const ushort* __restrict__ Mt,
                                               const ushort* __restrict__ wv,
                                               const int* __restrict__ traj,
                                               ushort* __restrict__ Yf,
                                               ushort* __restrict__ vt) {
    const bool is_y = blockIdx.x < 1024;
    const int n = is_y ? blockIdx.x : (blockIdx.x - 1024);
    const int xcd = n & 7;
    const int c = n >> 3;
    const int b = xcd + 8 * (c >> 5);
    const int rem = c & 31;
    const int rp = rem >> 2;
    const int x = rem & 3;
    if (rp * 128 >= traj[b]) return;  // masked panel: output never consumed
    const int row0 = b * Ln + rp * 128;
    const int col0 = x * 128;

    const ushort* Bop = is_y ? (Mt + (size_t)col0 * En) : (wv + (size_t)col0 * En);

    f32x4 acc[4][4] = {};
    nt_core_pipe<true>(Xf + (size_t)row0 * En, Bop, En, En, En, acc);

    const int tid = threadIdx.x;
    const int lane = tid & 63, wave = tid >> 6;
    const int wr = (wave >> 1) * 64, wc = (wave & 1) * 64;
    const int ln = lane & 15;

    if (is_y) {
#pragma unroll
        for (int m = 0; m < 4; ++m)
#pragma unroll
            for (int nn = 0; nn < 4; ++nn)
#pragma unroll
                for (int rr = 0; rr < 4; ++rr) {
                    const int gi = row0 + wr + m * 16 + (lane >> 4) * 4 + rr;
                    const int gj = col0 + wc + nn * 16 + ln;
                    Yf[(size_t)gi * En + gj] = f2h(acc[m][nn][rr]);
                }
    } else {
        const int lbase = rp * 128;
#pragma unroll
        for (int m = 0; m < 4; ++m)
#pragma unroll
            for (int nn = 0; nn < 4; ++nn) {
                const int gj = col0 + wc + nn * 16 + ln;
                const int l0 = lbase + wr + m * 16 + (lane >> 4) * 4;
                ushort4 u;
                u.x = f2bf(acc[m][nn][0]);
                u.y = f2bf(acc[m][nn][1]);
                u.z = f2bf(acc[m][nn][2]);
                u.w = f2bf(acc[m][nn][3]);
                *(ushort4*)(vt + ((size_t)b * On + gj) * Ln + l0) = u;
            }
    }
}

// ---------------------------------------------------------------------------
// Pass 2: S[b] = Y[b]*X[b]^T (plain fp16, K=512) + sum_k delta -> fp32.
// grid 2048; batch b -> XCD b%8. Skips fully-masked row panels.
// Unconditional batched delta epilogue (r13 lesson).
// ---------------------------------------------------------------------------
__global__ __launch_bounds__(256) void gemm_scores(const ushort* __restrict__ Yf,
                                                   const ushort* __restrict__ Xf,
                                                   const float* __restrict__ delta,
                                                   const int* __restrict__ traj,
                                                   float* __restrict__ S) {
    const int n = blockIdx.x;
    const int xcd = n & 7;
    const int c = n >> 3;
    const int b = (c / 64) * 8 + xcd;
    const int xy = c % 64;
    const int col0 = (xy & 7) * 128;
    const int row0 = (xy >> 3) * 128;
    if (row0 >= traj[b]) return;  // whole panel masked

    const size_t abase = ((size_t)b * Ln + row0) * En;
    const size_t bbase = ((size_t)b * Ln + col0) * En;

    f32x4 acc[4][4] = {};
    nt_core_pipe<true>(Yf + abase, Xf + bbase, En, En, En, acc);

    const int tid = threadIdx.x;
    const int lane = tid & 63, wave = tid >> 6;
    const int wr = (wave >> 1) * 64, wc = (wave & 1) * 64;
    const int ln = lane & 15;

#pragma unroll
    for (int m = 0; m < 4; ++m)
#pragma unroll
        for (int nn = 0; nn < 4; ++nn)
#pragma unroll
            for (int rr = 0; rr < 4; ++rr) {
                const int gi = row0 + wr + m * 16 + (lane >> 4) * 4 + rr;
                const int gj = col0 + wc + nn * 16 + ln;
                const float4 dv = *(const float4*)(delta + (((size_t)b * Ln + gi) * Ln + gj) * 4);
                S[((size_t)b * Ln + gi) * Ln + gj] = acc[m][nn][rr] + ((dv.x + dv.y) + (dv.z + dv.w));
            }
}

// ---------------------------------------------------------------------------
// Pass 3: full-row softmax (denom over ALL j), post-softmax mask, P bf16
// in place. Batch-aligned swizzle. Rows in fully-masked panels exit with
// no store (pv never reads their P).
// ---------------------------------------------------------------------------
__global__ __launch_bounds__(256) void softmax_kernel(float* __restrict__ S,
                                                      const int* __restrict__ traj) {
    const int n = blockIdx.x;
    const int xcd = n & 7;
    const int idx = n >> 3;
    const int b = xcd + 8 * (idx >> 10);
    const int i = idx & (Ln - 1);
    const int t = traj[b];
    if (i >= ((t + 127) & ~127)) return;  // fully-masked panel: P never read

    float* Srow = S + ((size_t)b * Ln + i) * Ln;
    ushort* Prow = (ushort*)Srow;
    const int tid = threadIdx.x;
    const int j0 = tid * 4;

    if (i >= t) {  // masked row inside boundary panel: pv reads it -> zero P
        ushort4 z = {0, 0, 0, 0};
        *(ushort4*)&Prow[j0] = z;
        return;
    }

    float4 v = *(const float4*)&Srow[j0];
    __shared__ float red[4];

    float m = fmaxf(fmaxf(v.x, v.y), fmaxf(v.z, v.w));
#pragma unroll
    for (int off = 32; off >= 1; off >>= 1) m = fmaxf(m, __shfl_xor(m, off));
    if ((tid & 63) == 0) red[tid >> 6] = m;
    __syncthreads();
    m = fmaxf(fmaxf(red[0], red[1]), fmaxf(red[2], red[3]));
    __syncthreads();

    float e0 = __expf(v.x - m), e1 = __expf(v.y - m), e2 = __expf(v.z - m), e3 = __expf(v.w - m);
    float s = (e0 + e1) + (e2 + e3);
#pragma unroll
    for (int off = 32; off >= 1; off >>= 1) s += __shfl_xor(s, off);
    if ((tid & 63) == 0) red[tid >> 6] = s;
    __syncthreads();
    s = (red[0] + red[1]) + (red[2] + red[3]);
    const float inv = 1.0f / s;

    ushort4 o;
    o.x = (j0 + 0 < t) ? f2bf(e0 * inv) : (ushort)0;
    o.y = (j0 + 1 < t) ? f2bf(e1 * inv) : (ushort)0;
    o.z = (j0 + 2 < t) ? f2bf(e2 * inv) : (ushort)0;
    o.w = (j0 + 3 < t) ? f2bf(e3 * inv) : (ushort)0;
    *(ushort4*)&Prow[j0] = o;
}

// ---------------------------------------------------------------------------
// Pass 4: out[b] = P[b] (bf16, stride 2048) * V[b] (bf16). K truncated to
// ceil32(t). Fully-masked panels store exact zeros.
// ---------------------------------------------------------------------------
__global__ __launch_bounds__(256) void gemm_pv(const ushort* __restrict__ P,
                                               const ushort* __restrict__ vt,
                                               const int* __restrict__ traj,
                                               float* __restrict__ out) {
    const int n = blockIdx.x;
    const int xcd = n & 7;
    const int c = n >> 3;
    const int b = (c / 32) * 8 + xcd;
    const int xy = c % 32;
    const int col0 = (xy & 3) * 128;
    const int row0 = (xy >> 2) * 128;
    const int t = traj[b];

    const int tid = threadIdx.x;

    if (row0 >= t) {  // whole output panel masked: exact zeros
        const float4 z = make_float4(0.f, 0.f, 0.f, 0.f);
        for (int i = tid; i < 128 * 32; i += 256) {
            const int r = i >> 5, c4 = (i & 31) * 4;
            *(float4*)&out[((size_t)b * Ln + row0 + r) * On + col0 + c4] = z;
        }
        return;
    }

    const int Kd = ((t + 31) >> 5) << 5;  // P[k]=0 for k>=t -> truncate

    f32x4 acc[4][4] = {};
    nt_core_pipe<false>(P + ((size_t)b * Ln + row0) * 2048,
                        vt + ((size_t)b * On + col0) * Ln, 2048, Ln, Kd, acc);

    const int lane = tid & 63, wave = tid >> 6;
    const int wr = (wave >> 1) * 64, wc = (wave & 1) * 64;
    const int ln = lane & 15;

#pragma unroll
    for (int m = 0; m < 4; ++m)
#pragma unroll
        for (int nn = 0; nn < 4; ++nn)
#pragma unroll
            for (int rr = 0; rr < 4; ++rr) {
                const int gi = row0 + wr + m * 16 + (lane >> 4) * 4 + rr;
                const int gj = col0 + wc + nn * 16 + ln;
                const float val = (gi < t) ? acc[m][nn][rr] : 0.f;
                out[((size_t)b * Ln + gi) * On + gj] = val;
            }
}

extern "C" void kernel_launch(void* const* d_in, const int* in_sizes, int n_in,
                              void* d_out, int out_size, void* d_ws, size_t ws_size,
                              hipStream_t stream) {
    const float* X = (const float*)d_in[0];      // [B, L, E]
    const float* delta = (const float*)d_in[1];  // [B, L, L, 4]
    const float* Wq = (const float*)d_in[2];     // [E, O]
    const float* Wk = (const float*)d_in[3];
    const float* Wv = (const float*)d_in[4];
    const int* traj = (const int*)d_in[5];       // [B]
    float* out = (float*)d_out;

    // ws layout (ushort units unless noted)
    const size_t NE = (size_t)Bn * Ln * On;  // 16.77M elements
    ushort* Mt = (ushort*)d_ws;              // En*En fp16
    ushort* wv = Mt + (size_t)En * En;       // En*En fp16
    ushort* Xf = wv + (size_t)En * En;       // NE fp16
    ushort* Yf = Xf + NE;                    // NE fp16
    ushort* vt = Yf + NE;                    // NE bf16 [B][O][L]
    float* S = (float*)(vt + NE);            // [B][L][L] fp32 / P bf16 in place

    prep_kernel<<<dim3(8512), 256, 0, stream>>>(X, Wq, Wk, Wv, Xf, wv, Mt);
    gemm_yv<<<dim3(2048), 256, 0, stream>>>(Xf, Mt, wv, traj, Yf, vt);
    gemm_scores<<<dim3(2048), 256, 0, stream>>>(Yf, Xf, delta, traj, S);
    softmax_kernel<<<dim3(Bn * Ln), 256, 0, stream>>>(S, traj);
    gemm_pv<<<dim3(1024), 256, 0, stream>>>((const ushort*)S, vt, traj, out);
}